// Round 8
// baseline (627.753 us; speedup 1.0000x reference)
//
#include <hip/hip_runtime.h>
#include <hip/hip_bf16.h>
#include <math.h>

// Problem constants
#define Bd   16
#define NPd  512
#define Nd   1024
#define Cd   1024
#define Hd   16
#define HDd  64
#define HIDd 4096
#define EPSd 1e-5f
#define MRd  (Bd * NPd)   // 8192 rows

typedef unsigned short u16;
typedef __bf16 bf16x8 __attribute__((ext_vector_type(8)));
typedef float  f32x4  __attribute__((ext_vector_type(4)));

// round-to-nearest-even f32 -> bf16 bits
__device__ __forceinline__ u16 f2bf(float f) {
    unsigned int u = __builtin_bit_cast(unsigned int, f);
    u = u + 0x7fffu + ((u >> 16) & 1u);
    return (u16)(u >> 16);
}

// async global->LDS, 16B per lane; LDS dest = wave-uniform base + lane*16.
__device__ __forceinline__ void async_load16(const void* g, void* l) {
    __builtin_amdgcn_global_load_lds(
        (const __attribute__((address_space(1))) void*)(uintptr_t)g,
        (__attribute__((address_space(3))) void*)(unsigned int)(uintptr_t)l,
        16, 0, 0);
}

// ---------------------------------------------------------------------------
// build_src: src[b*N+n] = token rank if slot updated else -1 (u8/i32 autodetect)
// ---------------------------------------------------------------------------
__global__ __launch_bounds__(256) void build_src(const void* __restrict__ mask_raw,
                                                 int* __restrict__ src) {
    const int b = blockIdx.x;
    const int t = threadIdx.x;
    const unsigned char* m8 = (const unsigned char*)mask_raw;
    const int* m32 = (const int*)mask_raw;

    int c = 0;
    #pragma unroll
    for (int i = 0; i < 4; i++) c += (m8[b * Nd + t * 4 + i] != 0) ? 1 : 0;
    #pragma unroll
    for (int off = 1; off < 64; off <<= 1) c += __shfl_xor(c, off);
    __shared__ int warr[4];
    if ((t & 63) == 0) warr[t >> 6] = c;
    __syncthreads();
    const int c8 = warr[0] + warr[1] + warr[2] + warr[3];
    const bool use8 = (c8 == NPd);

    int f[4];
    #pragma unroll
    for (int i = 0; i < 4; i++) {
        const int n = t * 4 + i;
        f[i] = use8 ? (m8[b * Nd + n] != 0) : (m32[b * Nd + n] != 0);
    }
    const int loc = f[0] + f[1] + f[2] + f[3];

    int sc_ = loc;
    #pragma unroll
    for (int off = 1; off < 64; off <<= 1) {
        const int u = __shfl_up(sc_, off);
        if ((t & 63) >= off) sc_ += u;
    }
    __shared__ int wtot[4];
    __syncthreads();
    if ((t & 63) == 63) wtot[t >> 6] = sc_;
    __syncthreads();
    int base = 0;
    for (int w = 0; w < (t >> 6); w++) base += wtot[w];

    int run = base + sc_ - loc;
    #pragma unroll
    for (int i = 0; i < 4; i++) {
        const int n = t * 4 + i;
        src[b * Nd + n] = f[i] ? run : -1;
        run += f[i];
    }
}

// ---------------------------------------------------------------------------
// LayerNorm over C=1024 -> bf16 output. One block (256 thr) per row.
// ---------------------------------------------------------------------------
__global__ __launch_bounds__(256) void ln_kernel(const float* __restrict__ x,
                                                 const float* __restrict__ g,
                                                 const float* __restrict__ bb,
                                                 u16* __restrict__ out) {
    const int row = blockIdx.x;
    const int t = threadIdx.x;
    const float* xr = x + (size_t)row * Cd;
    const float4 v = *(const float4*)(xr + t * 4);
    float s = v.x + v.y + v.z + v.w;
    float q = v.x * v.x + v.y * v.y + v.z * v.z + v.w * v.w;
    #pragma unroll
    for (int off = 1; off < 64; off <<= 1) {
        s += __shfl_xor(s, off);
        q += __shfl_xor(q, off);
    }
    __shared__ float ss[4], qq[4];
    if ((t & 63) == 0) { ss[t >> 6] = s; qq[t >> 6] = q; }
    __syncthreads();
    s = ss[0] + ss[1] + ss[2] + ss[3];
    q = qq[0] + qq[1] + qq[2] + qq[3];
    const float mu = s * (1.0f / Cd);
    const float var = q * (1.0f / Cd) - mu * mu;
    const float rs = rsqrtf(var + EPSd);
    const float4 gv = *(const float4*)(g + t * 4);
    const float4 bv = *(const float4*)(bb + t * 4);
    ushort4 r;
    r.x = f2bf((v.x - mu) * rs * gv.x + bv.x);
    r.y = f2bf((v.y - mu) * rs * gv.y + bv.y);
    r.z = f2bf((v.z - mu) * rs * gv.z + bv.z);
    r.w = f2bf((v.w - mu) * rs * gv.w + bv.w);
    *(ushort4*)(out + (size_t)row * Cd + t * 4) = r;
}

// ---------------------------------------------------------------------------
// Weight convert+transpose: W[K,N] f32 -> Wt[N,K] bf16. 32x32 tiles.
// ---------------------------------------------------------------------------
__global__ __launch_bounds__(256) void conv_t(const float* __restrict__ W,
                                              u16* __restrict__ Wt,
                                              int K, int N) {
    __shared__ float tile[32][33];
    const int k0 = blockIdx.y * 32;
    const int n0 = blockIdx.x * 32;
    const int t = threadIdx.x;
    const int row = t >> 3, c4 = (t & 7) * 4;
    const float4 v = *(const float4*)(W + (size_t)(k0 + row) * N + n0 + c4);
    tile[row][c4 + 0] = v.x;
    tile[row][c4 + 1] = v.y;
    tile[row][c4 + 2] = v.z;
    tile[row][c4 + 3] = v.w;
    __syncthreads();
    ushort4 o;
    o.x = f2bf(tile[c4 + 0][row]);
    o.y = f2bf(tile[c4 + 1][row]);
    o.z = f2bf(tile[c4 + 2][row]);
    o.w = f2bf(tile[c4 + 3][row]);
    *(ushort4*)(Wt + (size_t)(n0 + row) * K + k0 + c4) = o;
}

// ---------------------------------------------------------------------------
// bf16 MFMA GEMM (128x128): C[M,Nn] = A[M,K] @ Wt[Nn,K]^T + bias (+epi)
// EPI: 0 = bias, 1 = bias + fp32 residual, 2 = bias + exact GELU
// 128x128 tile, BK=32, 4-deep LDS ring (64 KB), DEPTH-3 prefetch with
// counted vmcnt(8): 12 loads (3 tiles) in flight across barriers, retiring
// one tile per step -> each staged load gets ~3 MFMA-phases to land.
// Chunk-XOR swizzle (2-way free banks), chunked XCD remap.
// THE single GEMM for all four layers (R7: improved qkv/proj/FC2; R6/R7
// showed wider-tile variants are fragile to occupancy/env — converged here).
// ---------------------------------------------------------------------------
template <int EPI, typename OUT_T>
__global__ __launch_bounds__(256) void gemm_mfma(const u16* __restrict__ A,
                                                 const u16* __restrict__ Wt,
                                                 const float* __restrict__ bias,
                                                 const float* __restrict__ res,
                                                 OUT_T* __restrict__ out,
                                                 int K, int Nn) {
    __shared__ u16 As[4][128 * 32];
    __shared__ u16 Bs[4][128 * 32];

    const int t = threadIdx.x;
    const int L = t & 63;
    const int w = t >> 6;
    const int wm = w >> 1, wn = w & 1;

    // chunked XCD swizzle (bijective: all grids are multiples of 8)
    const int gx = gridDim.x;
    const int nwg = gx * gridDim.y;
    int id = blockIdx.y * gx + blockIdx.x;
    id = (id & 7) * (nwg >> 3) + (id >> 3);
    const int m0 = (id / gx) * 128;
    const int n0 = (id % gx) * 128;

    const int srow = 32 * w + (L >> 2);
    const int scol = (((L & 3) ^ ((L >> 3) & 3)) * 8);
    const u16* ap0 = A  + (size_t)(m0 + srow) * K + scol;
    const u16* ap1 = ap0 + (size_t)16 * K;
    const u16* bp0 = Wt + (size_t)(n0 + srow) * K + scol;
    const u16* bp1 = bp0 + (size_t)16 * K;

    f32x4 acc[4][4];
    const f32x4 zero = {0.f, 0.f, 0.f, 0.f};
    #pragma unroll
    for (int i = 0; i < 4; i++)
        #pragma unroll
        for (int j = 0; j < 4; j++) acc[i][j] = zero;

    const int rr = L & 15;
    const int frag_off = rr * 32 + ((((L >> 4)) ^ ((rr >> 1) & 3)) * 8);
    const int nsteps = K >> 5;

#define STAGE_G(s_, kt_) do {                                   \
        const int off_ = (kt_) << 5;                            \
        async_load16(ap0 + off_, &As[s_][w * 1024]);            \
        async_load16(ap1 + off_, &As[s_][w * 1024 + 512]);      \
        async_load16(bp0 + off_, &Bs[s_][w * 1024]);            \
        async_load16(bp1 + off_, &Bs[s_][w * 1024 + 512]);      \
    } while (0)

    // prologue: stage tiles 0..2; wait only for tile 0 (8 newest in flight)
    STAGE_G(0, 0);
    STAGE_G(1, 1);
    STAGE_G(2, 2);
    asm volatile("s_waitcnt vmcnt(8)" ::: "memory");
    __builtin_amdgcn_s_barrier();

    int cur = 0;
    for (int kt = 0; kt < nsteps; kt++) {
        if (kt + 3 < nsteps) STAGE_G((cur + 3) & 3, kt + 3);

        bf16x8 a[4], b[4];
        #pragma unroll
        for (int i = 0; i < 4; i++) {
            a[i] = *(const bf16x8*)&As[cur][(wm * 64 + i * 16) * 32 + frag_off];
            b[i] = *(const bf16x8*)&Bs[cur][(wn * 64 + i * 16) * 32 + frag_off];
        }
        #pragma unroll
        for (int i = 0; i < 4; i++)
            #pragma unroll
            for (int j = 0; j < 4; j++)
                acc[i][j] = __builtin_amdgcn_mfma_f32_16x16x32_bf16(a[i], b[j], acc[i][j], 0, 0, 0);

        // retire exactly tile kt+1's 4 loads; newer tiles stay in flight
        const int rem = nsteps - kt;
        if (rem > 3)      asm volatile("s_waitcnt vmcnt(8)" ::: "memory");
        else if (rem == 3) asm volatile("s_waitcnt vmcnt(4)" ::: "memory");
        else               asm volatile("s_waitcnt vmcnt(0)" ::: "memory");
        __builtin_amdgcn_s_barrier();
        cur = (cur + 1) & 3;
    }
#undef STAGE_G

    const int cn = n0 + wn * 64 + (L & 15);
    const int cm = m0 + wm * 64 + (L >> 4) * 4;
    #pragma unroll
    for (int i = 0; i < 4; i++) {
        #pragma unroll
        for (int j = 0; j < 4; j++) {
            const int nn = cn + j * 16;
            const float bv = bias[nn];
            #pragma unroll
            for (int r = 0; r < 4; r++) {
                const int mm = cm + i * 16 + r;
                float v = acc[i][j][r] + bv;
                if (EPI == 2) v = 0.5f * v * (1.0f + erff(v * 0.70710678118654752f));
                if (EPI == 1) v += res[(size_t)mm * Nn + nn];
                if constexpr (sizeof(OUT_T) == 2) out[(size_t)mm * Nn + nn] = (OUT_T)f2bf(v);
                else out[(size_t)mm * Nn + nn] = v;
            }
        }
    }
}

// ---------------------------------------------------------------------------
// kv_cast: gather full K/V (cache or new tokens via src) into bf16:
//   Kb[B,H,N,HD]  (K rows)    Vtb[B,H,HD,N]  (V transposed)
// Grid: B*H*(N/64) blocks, 256 threads. LDS transpose for V.
// ---------------------------------------------------------------------------
__global__ __launch_bounds__(256) void kv_cast(const u16* __restrict__ qkv,
                                               const float* __restrict__ ck,
                                               const float* __restrict__ cv,
                                               const int* __restrict__ srcArr,
                                               u16* __restrict__ Kb,
                                               u16* __restrict__ Vtb) {
    const int id = blockIdx.x;
    const int nt = id & 15, hh = (id >> 4) & 15, b = id >> 8;
    const int t = threadIdx.x;
    __shared__ u16 Vl[64][72];

    const int row = t >> 2;            // key row 0..63
    const int dd = (t & 3) * 16;       // dim chunk
    const int n = nt * 64 + row;
    const int sidx = srcArr[b * Nd + n];

    u16 kv16[16], vv16[16];
    if (sidx >= 0) {
        const u16* kp = qkv + (size_t)(b * NPd + sidx) * 3072 + Cd + hh * 64 + dd;
        const u16* vp = kp + Cd;
        *(ulonglong2*)&kv16[0] = *(const ulonglong2*)kp;
        *(ulonglong2*)&kv16[8] = *(const ulonglong2*)(kp + 8);
        *(ulonglong2*)&vv16[0] = *(const ulonglong2*)vp;
        *(ulonglong2*)&vv16[8] = *(const ulonglong2*)(vp + 8);
    } else {
        const float* kp = ck + ((size_t)((b * Hd + hh) * Nd + n)) * HDd + dd;
        const float* vp = cv + ((size_t)((b * Hd + hh) * Nd + n)) * HDd + dd;
        #pragma unroll
        for (int c = 0; c < 4; c++) {
            const float4 kc4 = *(const float4*)(kp + c * 4);
            const float4 vc4 = *(const float4*)(vp + c * 4);
            kv16[c * 4 + 0] = f2bf(kc4.x); kv16[c * 4 + 1] = f2bf(kc4.y);
            kv16[c * 4 + 2] = f2bf(kc4.z); kv16[c * 4 + 3] = f2bf(kc4.w);
            vv16[c * 4 + 0] = f2bf(vc4.x); vv16[c * 4 + 1] = f2bf(vc4.y);
            vv16[c * 4 + 2] = f2bf(vc4.z); vv16[c * 4 + 3] = f2bf(vc4.w);
        }
    }

    u16* ko = Kb + ((size_t)((b * Hd + hh) * Nd + n)) * HDd + dd;
    *(ulonglong2*)ko = *(ulonglong2*)&kv16[0];
    *(ulonglong2*)(ko + 8) = *(ulonglong2*)&kv16[8];

    #pragma unroll
    for (int i = 0; i < 16; i++) Vl[row][dd + i] = vv16[i];
    __syncthreads();

    const int d = t >> 2, nc = (t & 3) * 16;
    u16 ov[16];
    #pragma unroll
    for (int i = 0; i < 16; i++) ov[i] = Vl[nc + i][d];
    u16* vo = Vtb + ((size_t)((b * Hd + hh) * HDd + d)) * Nd + nt * 64 + nc;
    *(ulonglong2*)vo = *(ulonglong2*)&ov[0];
    *(ulonglong2*)(vo + 8) = *(ulonglong2*)&ov[8];
}

// ---------------------------------------------------------------------------
// MFMA flash attention. Grid (bh=256, qt=8), 256 thr = 4 waves.
// Swapped QK^T (S^T = mfma(K,Q)) -> each lane owns one q column: softmax
// max/sum are in-register trees + 2 shfl_xor. P written as packed ushort4.
// Defer-max (THR=8) skips acc rescale on most tiles. XCD remap keeps per-XCD
// KV working set ~2MB (L2-resident).
// ---------------------------------------------------------------------------
__global__ __launch_bounds__(256) void attn_mfma(const u16* __restrict__ qkv,
                                                 const u16* __restrict__ Kb,
                                                 const u16* __restrict__ Vtb,
                                                 u16* __restrict__ attno) {
    const int orig = blockIdx.y * 256 + blockIdx.x;
    const int xc = orig & 7, pos = orig >> 3;
    const int bh = (xc << 5) | (pos >> 3);
    const int qt = pos & 7;
    const int b = bh >> 4, hh = bh & 15;
    const int t = threadIdx.x;
    const int L = t & 63;
    const int w = t >> 6;
    const int g = L >> 4;        // 0..3: key sub-group / k-chunk
    const int q16 = L & 15;      // lane's softmax q (within wave block)

    __shared__ u16 Qs[4096];          // [64 q][64 k] swizzled
    __shared__ u16 Ks[4096];          // [64 key][64 dim] swizzled
    __shared__ u16 Vs[4096];          // [64 dim][64 key] swizzled
    __shared__ u16 Ps[4][16 * 72];    // per-wave P [16 q][64 key], pad 72

    const size_t kbase = (size_t)((b * Hd + hh) * Nd) * HDd;
    const size_t vbase = (size_t)((b * Hd + hh) * HDd) * Nd;

    // stage Q once (8 issues of 8 rows; wave w does rows 16w..16w+15)
    #pragma unroll
    for (int j = 0; j < 2; j++) {
        const int row = 16 * w + 8 * j + (L >> 3);
        const int ch = (L & 7) ^ (row & 7);
        const u16* gq = qkv + (size_t)(b * NPd + qt * 64 + row) * 3072 + hh * 64 + ch * 8;
        async_load16(gq, Qs + (16 * w + 8 * j) * 64);
    }

    f32x4 acc[4];
    const f32x4 zero = {0.f, 0.f, 0.f, 0.f};
    #pragma unroll
    for (int nb = 0; nb < 4; nb++) acc[nb] = zero;
    float m_run = -INFINITY;   // running max for q = w*16+q16 (scaled units)
    float l_run = 0.f;         // running denom for q = w*16+q16

    bf16x8 aq0, aq1;           // Q frag (constant across key tiles)

    for (int kt = 0; kt < 16; kt++) {
        __syncthreads();    // prev tile consumed
        #pragma unroll
        for (int j = 0; j < 2; j++) {
            const int row = 16 * w + 8 * j + (L >> 3);
            const int ch = (L & 7) ^ (row & 7);
            async_load16(Kb + kbase + (size_t)(kt * 64 + row) * 64 + ch * 8,
                         Ks + (16 * w + 8 * j) * 64);
            async_load16(Vtb + vbase + (size_t)row * Nd + kt * 64 + ch * 8,
                         Vs + (16 * w + 8 * j) * 64);
        }
        __syncthreads();    // staging (and Q on kt=0) complete

        if (kt == 0) {      // hoisted Q A-frags (rows w*16 + q16)
            const int qrow = 16 * w + q16;
            aq0 = *(const bf16x8*)&Qs[qrow * 64 + ((g       ^ (L & 7)) * 8)];
            aq1 = *(const bf16x8*)&Qs[qrow * 64 + (((4 + g) ^ (L & 7)) * 8)];
        }

        // S^T = K Q^T: swapped operands. s[kb][r] = S[q=w*16+q16][key=kb*16+g*4+r]
        f32x4 s[4];
        #pragma unroll
        for (int kb = 0; kb < 4; kb++) {
            const int krow = kb * 16 + q16;
            const bf16x8 bk0 = *(const bf16x8*)&Ks[krow * 64 + ((g       ^ (L & 7)) * 8)];
            const bf16x8 bk1 = *(const bf16x8*)&Ks[krow * 64 + (((4 + g) ^ (L & 7)) * 8)];
            s[kb] = __builtin_amdgcn_mfma_f32_16x16x32_bf16(bk0, aq0, zero, 0, 0, 0);
            s[kb] = __builtin_amdgcn_mfma_f32_16x16x32_bf16(bk1, aq1, s[kb], 0, 0, 0);
        }

        // in-register row max (16 values for this lane's q), then 2 shfl
        float m0 = fmaxf(fmaxf(s[0][0], s[0][1]), fmaxf(s[0][2], s[0][3]));
        float m1 = fmaxf(fmaxf(s[1][0], s[1][1]), fmaxf(s[1][2], s[1][3]));
        float m2 = fmaxf(fmaxf(s[2][0], s[2][1]), fmaxf(s[2][2], s[2][3]));
        float m3 = fmaxf(fmaxf(s[3][0], s[3][1]), fmaxf(s[3][2], s[3][3]));
        float mx = fmaxf(fmaxf(m0, m1), fmaxf(m2, m3)) * 0.125f;
        mx = fmaxf(mx, __shfl_xor(mx, 16));
        mx = fmaxf(mx, __shfl_xor(mx, 32));

        // defer-max: rescale only if some q's max grew past threshold
        if (__any(mx > m_run + 8.f)) {
            const float mn = fmaxf(m_run, mx);
            const float al = __expf(m_run - mn);
            m_run = mn;
            l_run *= al;
            float alr[4];
            #pragma unroll
            for (int r = 0; r < 4; r++) alr[r] = __shfl(al, g * 4 + r);
            #pragma unroll
            for (int nb = 0; nb < 4; nb++)
                #pragma unroll
                for (int r = 0; r < 4; r++) acc[nb][r] *= alr[r];
        }

        // P = exp(S*scale - m), packed write + in-register sum
        u16* pw = &Ps[w][0];
        float ps = 0.f;
        #pragma unroll
        for (int kb = 0; kb < 4; kb++) {
            float p0 = __expf(fmaf(s[kb][0], 0.125f, -m_run));
            float p1 = __expf(fmaf(s[kb][1], 0.125f, -m_run));
            float p2 = __expf(fmaf(s[kb][2], 0.125f, -m_run));
            float p3 = __expf(fmaf(s[kb][3], 0.125f, -m_run));
            ps += (p0 + p1) + (p2 + p3);
            ushort4 v4;
            v4.x = f2bf(p0); v4.y = f2bf(p1); v4.z = f2bf(p2); v4.w = f2bf(p3);
            *(ushort4*)&pw[q16 * 72 + kb * 16 + g * 4] = v4;
        }
        ps += __shfl_xor(ps, 16);
        ps += __shfl_xor(ps, 32);
        l_run += ps;

        // PV: A = P [q][key], B = Vt [dim][key]
        const bf16x8 ap0 = *(const bf16x8*)&Ps[w][q16 * 72 +      g * 8];
        const bf16x8 ap1 = *(const bf16x8*)&Ps[w][q16 * 72 + 32 + g * 8];
        #pragma unroll
        for (int nb = 0; nb < 4; nb++) {
            const int drow = nb * 16 + q16;
            const bf16x8 bv0 = *(const bf16x8*)&Vs[drow * 64 + ((g       ^ (L & 7)) * 8)];
            const bf16x8 bv1 = *(const bf16x8*)&Vs[drow * 64 + (((4 + g) ^ (L & 7)) * 8)];
            acc[nb] = __builtin_amdgcn_mfma_f32_16x16x32_bf16(ap0, bv0, acc[nb], 0, 0, 0);
            acc[nb] = __builtin_amdgcn_mfma_f32_16x16x32_bf16(ap1, bv1, acc[nb], 0, 0, 0);
        }
    }

    // redistribute 1/l to this lane's acc rows (q' = g*4+r)
    const float invq = 1.0f / l_run;
    float inv[4];
    #pragma unroll
    for (int r = 0; r < 4; r++) inv[r] = __shfl(invq, g * 4 + r);
    #pragma unroll
    for (int nb = 0; nb < 4; nb++)
        #pragma unroll
        for (int r = 0; r < 4; r++) {
            const int q = qt * 64 + w * 16 + g * 4 + r;
            const int d = nb * 16 + q16;
            attno[(size_t)(b * NPd + q) * Cd + hh * 64 + d] = f2bf(acc[nb][r] * inv[r]);
        }
}

// ---------------------------------------------------------------------------
extern "C" void kernel_launch(void* const* d_in, const int* in_sizes, int n_in,
                              void* d_out, int out_size, void* d_ws, size_t ws_size,
                              hipStream_t stream) {
    const float* x       = (const float*)d_in[0];
    const float* cache_k = (const float*)d_in[1];
    const float* cache_v = (const float*)d_in[2];
    const void*  mask    = d_in[3];
    const float* qkv_w   = (const float*)d_in[4];
    const float* qkv_b   = (const float*)d_in[5];
    const float* proj_w  = (const float*)d_in[6];
    const float* proj_b  = (const float*)d_in[7];
    const float* n1_g    = (const float*)d_in[8];
    const float* n1_b    = (const float*)d_in[9];
    const float* n2_g    = (const float*)d_in[10];
    const float* n2_b    = (const float*)d_in[11];
    const float* fc1_w   = (const float*)d_in[12];
    const float* fc1_b   = (const float*)d_in[13];
    const float* fc2_w   = (const float*)d_in[14];
    const float* fc2_b   = (const float*)d_in[15];
    float* out = (float*)d_out;

    const size_t MR = (size_t)Bd * NPd;           // 8192 rows
    char* ws = (char*)d_ws;
    int*   srcArr = (int*)ws;                                     // 64 KB
    float* x2     = (float*)(ws + 65536);                         // 33.55 MB
    u16*   h      = (u16*)(x2 + MR * Cd);                         // 16.78 MB
    u16*   attno  = h + MR * Cd;                                  // 16.78 MB
    u16*   qkv    = attno + MR * Cd;                              // 50.33 MB bf16
    u16*   Kb     = qkv + MR * 3 * Cd;                            // 33.55 MB
    u16*   Vtb    = Kb + (size_t)Bd * Hd * Nd * HDd;              // 33.55 MB
    u16*   m1     = qkv;            // 67.1 MB, reuses dead qkv+Kb region
    u16*   qkv_wt = Vtb + (size_t)Bd * Hd * Nd * HDd;             // 6.29 MB
    u16*   proj_wt= qkv_wt + (size_t)3 * Cd * Cd;                 // 2.10 MB
    u16*   fc1_wt = proj_wt + (size_t)Cd * Cd;                    // 8.39 MB
    u16*   fc2_wt = fc1_wt + (size_t)Cd * HIDd;                   // 8.39 MB

    build_src<<<Bd, 256, 0, stream>>>(mask, srcArr);
    conv_t<<<dim3(3 * Cd / 32, Cd / 32),  256, 0, stream>>>(qkv_w,  qkv_wt,  Cd,   3 * Cd);
    conv_t<<<dim3(Cd / 32, Cd / 32),      256, 0, stream>>>(proj_w, proj_wt, Cd,   Cd);
    conv_t<<<dim3(HIDd / 32, Cd / 32),    256, 0, stream>>>(fc1_w,  fc1_wt,  Cd,   HIDd);
    conv_t<<<dim3(Cd / 32, HIDd / 32),    256, 0, stream>>>(fc2_w,  fc2_wt,  HIDd, Cd);

    ln_kernel<<<MR, 256, 0, stream>>>(x, n1_g, n1_b, h);
    // qkv: 128x128 depth-3 (24 x 64 = 1536 blocks)
    gemm_mfma<0, u16><<<dim3(3 * Cd / 128, MR / 128), 256, 0, stream>>>(
        h, qkv_wt, qkv_b, nullptr, qkv, Cd, 3 * Cd);
    kv_cast<<<Bd * Hd * (Nd / 64), 256, 0, stream>>>(qkv, cache_k, cache_v, srcArr, Kb, Vtb);
    attn_mfma<<<dim3(Bd * Hd, NPd / 64), 256, 0, stream>>>(qkv, Kb, Vtb, attno);
    // proj: 128x128 depth-3 (512 blocks)
    gemm_mfma<1, float><<<dim3(Cd / 128, MR / 128), 256, 0, stream>>>(
        attno, proj_wt, proj_b, x, x2, Cd, Cd);
    ln_kernel<<<MR, 256, 0, stream>>>(x2, n2_g, n2_b, h);
    // fc1: 128x128 depth-3 (32 x 64 = 2048 blocks)
    gemm_mfma<2, u16><<<dim3(HIDd / 128, MR / 128), 256, 0, stream>>>(
        h, fc1_wt, fc1_b, nullptr, m1, Cd, HIDd);
    // fc2: 128x128 depth-3 (512 blocks)
    gemm_mfma<1, float><<<dim3(Cd / 128, MR / 128), 256, 0, stream>>>(
        m1, fc2_wt, fc2_b, x2, out, HIDd, Cd);
}

// Round 9
// 597.312 us; speedup vs baseline: 1.0510x; 1.0510x over previous
//
#include <hip/hip_runtime.h>
#include <hip/hip_bf16.h>
#include <math.h>

// Problem constants
#define Bd   16
#define NPd  512
#define Nd   1024
#define Cd   1024
#define Hd   16
#define HDd  64
#define HIDd 4096
#define EPSd 1e-5f
#define MRd  (Bd * NPd)   // 8192 rows

typedef unsigned short u16;
typedef __bf16 bf16x8 __attribute__((ext_vector_type(8)));
typedef float  f32x4  __attribute__((ext_vector_type(4)));

// round-to-nearest-even f32 -> bf16 bits
__device__ __forceinline__ u16 f2bf(float f) {
    unsigned int u = __builtin_bit_cast(unsigned int, f);
    u = u + 0x7fffu + ((u >> 16) & 1u);
    return (u16)(u >> 16);
}

// async global->LDS, 16B per lane; LDS dest = wave-uniform base + lane*16.
__device__ __forceinline__ void async_load16(const void* g, void* l) {
    __builtin_amdgcn_global_load_lds(
        (const __attribute__((address_space(1))) void*)(uintptr_t)g,
        (__attribute__((address_space(3))) void*)(unsigned int)(uintptr_t)l,
        16, 0, 0);
}

// ---------------------------------------------------------------------------
// build_src: src[b*N+n] = token rank if slot updated else -1 (u8/i32 autodetect)
// ---------------------------------------------------------------------------
__global__ __launch_bounds__(256) void build_src(const void* __restrict__ mask_raw,
                                                 int* __restrict__ src) {
    const int b = blockIdx.x;
    const int t = threadIdx.x;
    const unsigned char* m8 = (const unsigned char*)mask_raw;
    const int* m32 = (const int*)mask_raw;

    int c = 0;
    #pragma unroll
    for (int i = 0; i < 4; i++) c += (m8[b * Nd + t * 4 + i] != 0) ? 1 : 0;
    #pragma unroll
    for (int off = 1; off < 64; off <<= 1) c += __shfl_xor(c, off);
    __shared__ int warr[4];
    if ((t & 63) == 0) warr[t >> 6] = c;
    __syncthreads();
    const int c8 = warr[0] + warr[1] + warr[2] + warr[3];
    const bool use8 = (c8 == NPd);

    int f[4];
    #pragma unroll
    for (int i = 0; i < 4; i++) {
        const int n = t * 4 + i;
        f[i] = use8 ? (m8[b * Nd + n] != 0) : (m32[b * Nd + n] != 0);
    }
    const int loc = f[0] + f[1] + f[2] + f[3];

    int sc_ = loc;
    #pragma unroll
    for (int off = 1; off < 64; off <<= 1) {
        const int u = __shfl_up(sc_, off);
        if ((t & 63) >= off) sc_ += u;
    }
    __shared__ int wtot[4];
    __syncthreads();
    if ((t & 63) == 63) wtot[t >> 6] = sc_;
    __syncthreads();
    int base = 0;
    for (int w = 0; w < (t >> 6); w++) base += wtot[w];

    int run = base + sc_ - loc;
    #pragma unroll
    for (int i = 0; i < 4; i++) {
        const int n = t * 4 + i;
        src[b * Nd + n] = f[i] ? run : -1;
        run += f[i];
    }
}

// ---------------------------------------------------------------------------
// LayerNorm over C=1024 -> bf16 output. One block (256 thr) per row.
// ---------------------------------------------------------------------------
__global__ __launch_bounds__(256) void ln_kernel(const float* __restrict__ x,
                                                 const float* __restrict__ g,
                                                 const float* __restrict__ bb,
                                                 u16* __restrict__ out) {
    const int row = blockIdx.x;
    const int t = threadIdx.x;
    const float* xr = x + (size_t)row * Cd;
    const float4 v = *(const float4*)(xr + t * 4);
    float s = v.x + v.y + v.z + v.w;
    float q = v.x * v.x + v.y * v.y + v.z * v.z + v.w * v.w;
    #pragma unroll
    for (int off = 1; off < 64; off <<= 1) {
        s += __shfl_xor(s, off);
        q += __shfl_xor(q, off);
    }
    __shared__ float ss[4], qq[4];
    if ((t & 63) == 0) { ss[t >> 6] = s; qq[t >> 6] = q; }
    __syncthreads();
    s = ss[0] + ss[1] + ss[2] + ss[3];
    q = qq[0] + qq[1] + qq[2] + qq[3];
    const float mu = s * (1.0f / Cd);
    const float var = q * (1.0f / Cd) - mu * mu;
    const float rs = rsqrtf(var + EPSd);
    const float4 gv = *(const float4*)(g + t * 4);
    const float4 bv = *(const float4*)(bb + t * 4);
    ushort4 r;
    r.x = f2bf((v.x - mu) * rs * gv.x + bv.x);
    r.y = f2bf((v.y - mu) * rs * gv.y + bv.y);
    r.z = f2bf((v.z - mu) * rs * gv.z + bv.z);
    r.w = f2bf((v.w - mu) * rs * gv.w + bv.w);
    *(ushort4*)(out + (size_t)row * Cd + t * 4) = r;
}

// ---------------------------------------------------------------------------
// Weight convert+transpose: W[K,N] f32 -> Wt[N,K] bf16. 32x32 tiles.
// ---------------------------------------------------------------------------
__global__ __launch_bounds__(256) void conv_t(const float* __restrict__ W,
                                              u16* __restrict__ Wt,
                                              int K, int N) {
    __shared__ float tile[32][33];
    const int k0 = blockIdx.y * 32;
    const int n0 = blockIdx.x * 32;
    const int t = threadIdx.x;
    const int row = t >> 3, c4 = (t & 7) * 4;
    const float4 v = *(const float4*)(W + (size_t)(k0 + row) * N + n0 + c4);
    tile[row][c4 + 0] = v.x;
    tile[row][c4 + 1] = v.y;
    tile[row][c4 + 2] = v.z;
    tile[row][c4 + 3] = v.w;
    __syncthreads();
    ushort4 o;
    o.x = f2bf(tile[c4 + 0][row]);
    o.y = f2bf(tile[c4 + 1][row]);
    o.z = f2bf(tile[c4 + 2][row]);
    o.w = f2bf(tile[c4 + 3][row]);
    *(ushort4*)(Wt + (size_t)(n0 + row) * K + k0 + c4) = o;
}

// ---------------------------------------------------------------------------
// bf16 MFMA GEMM: C[M,Nn] = A[M,K] @ Wt[Nn,K]^T + bias (+epi)
// EPI: 0 = bias, 1 = bias + fp32 residual, 2 = bias + exact GELU
// EXACT Round-4 config (best stable measurement: FC1 109us, occ 29%):
// 128x128 tile, BK=32, 3-deep LDS ring (48 KB -> 3 blocks/CU), depth-2
// prefetch, counted vmcnt(4), raw s_barrier, chunk-XOR swizzle (2-way free),
// chunked XCD remap. R6-R8 established: wave count > pipeline depth here;
// wider tiles and deeper rings both lose occupancy and regress.
// ---------------------------------------------------------------------------
template <int EPI, typename OUT_T>
__global__ __launch_bounds__(256) void gemm_mfma(const u16* __restrict__ A,
                                                 const u16* __restrict__ Wt,
                                                 const float* __restrict__ bias,
                                                 const float* __restrict__ res,
                                                 OUT_T* __restrict__ out,
                                                 int K, int Nn) {
    __shared__ u16 As[3][128 * 32];
    __shared__ u16 Bs[3][128 * 32];

    const int t = threadIdx.x;
    const int L = t & 63;
    const int w = t >> 6;
    const int wm = w >> 1, wn = w & 1;

    // chunked XCD swizzle (bijective: all grids are multiples of 8)
    const int gx = gridDim.x;
    const int nwg = gx * gridDim.y;
    int id = blockIdx.y * gx + blockIdx.x;
    id = (id & 7) * (nwg >> 3) + (id >> 3);
    const int m0 = (id / gx) * 128;
    const int n0 = (id % gx) * 128;

    const int srow = 32 * w + (L >> 2);
    const int scol = (((L & 3) ^ ((L >> 3) & 3)) * 8);
    const u16* ap0 = A  + (size_t)(m0 + srow) * K + scol;
    const u16* ap1 = ap0 + (size_t)16 * K;
    const u16* bp0 = Wt + (size_t)(n0 + srow) * K + scol;
    const u16* bp1 = bp0 + (size_t)16 * K;

    f32x4 acc[4][4];
    const f32x4 zero = {0.f, 0.f, 0.f, 0.f};
    #pragma unroll
    for (int i = 0; i < 4; i++)
        #pragma unroll
        for (int j = 0; j < 4; j++) acc[i][j] = zero;

    const int rr = L & 15;
    const int frag_off = rr * 32 + ((((L >> 4)) ^ ((rr >> 1) & 3)) * 8);
    const int nsteps = K >> 5;

#define STAGE_G(s_, kt_) do {                                   \
        const int off_ = (kt_) << 5;                            \
        async_load16(ap0 + off_, &As[s_][w * 1024]);            \
        async_load16(ap1 + off_, &As[s_][w * 1024 + 512]);      \
        async_load16(bp0 + off_, &Bs[s_][w * 1024]);            \
        async_load16(bp1 + off_, &Bs[s_][w * 1024 + 512]);      \
    } while (0)

    STAGE_G(0, 0);
    STAGE_G(1, 1);
    asm volatile("s_waitcnt vmcnt(4)" ::: "memory");
    __builtin_amdgcn_s_barrier();

    int cur = 0;
    for (int kt = 0; kt < nsteps; kt++) {
        if (kt + 2 < nsteps) {
            int s2 = cur + 2; if (s2 >= 3) s2 -= 3;
            STAGE_G(s2, kt + 2);
        }

        bf16x8 a[4], b[4];
        #pragma unroll
        for (int i = 0; i < 4; i++) {
            a[i] = *(const bf16x8*)&As[cur][(wm * 64 + i * 16) * 32 + frag_off];
            b[i] = *(const bf16x8*)&Bs[cur][(wn * 64 + i * 16) * 32 + frag_off];
        }
        #pragma unroll
        for (int i = 0; i < 4; i++)
            #pragma unroll
            for (int j = 0; j < 4; j++)
                acc[i][j] = __builtin_amdgcn_mfma_f32_16x16x32_bf16(a[i], b[j], acc[i][j], 0, 0, 0);

        if (kt + 2 < nsteps) asm volatile("s_waitcnt vmcnt(4)" ::: "memory");
        else                 asm volatile("s_waitcnt vmcnt(0)" ::: "memory");
        __builtin_amdgcn_s_barrier();
        cur = (cur + 1 == 3) ? 0 : cur + 1;
    }
#undef STAGE_G

    const int cn = n0 + wn * 64 + (L & 15);
    const int cm = m0 + wm * 64 + (L >> 4) * 4;
    #pragma unroll
    for (int i = 0; i < 4; i++) {
        #pragma unroll
        for (int j = 0; j < 4; j++) {
            const int nn = cn + j * 16;
            const float bv = bias[nn];
            #pragma unroll
            for (int r = 0; r < 4; r++) {
                const int mm = cm + i * 16 + r;
                float v = acc[i][j][r] + bv;
                if (EPI == 2) v = 0.5f * v * (1.0f + erff(v * 0.70710678118654752f));
                if (EPI == 1) v += res[(size_t)mm * Nn + nn];
                if constexpr (sizeof(OUT_T) == 2) out[(size_t)mm * Nn + nn] = (OUT_T)f2bf(v);
                else out[(size_t)mm * Nn + nn] = v;
            }
        }
    }
}

// ---------------------------------------------------------------------------
// kv_cast: gather full K/V (cache or new tokens via src) into bf16:
//   Kb[B,H,N,HD]  (K rows)    Vtb[B,H,HD,N]  (V transposed)
// Grid: B*H*(N/64) blocks, 256 threads. LDS transpose for V.
// ---------------------------------------------------------------------------
__global__ __launch_bounds__(256) void kv_cast(const u16* __restrict__ qkv,
                                               const float* __restrict__ ck,
                                               const float* __restrict__ cv,
                                               const int* __restrict__ srcArr,
                                               u16* __restrict__ Kb,
                                               u16* __restrict__ Vtb) {
    const int id = blockIdx.x;
    const int nt = id & 15, hh = (id >> 4) & 15, b = id >> 8;
    const int t = threadIdx.x;
    __shared__ u16 Vl[64][72];

    const int row = t >> 2;            // key row 0..63
    const int dd = (t & 3) * 16;       // dim chunk
    const int n = nt * 64 + row;
    const int sidx = srcArr[b * Nd + n];

    u16 kv16[16], vv16[16];
    if (sidx >= 0) {
        const u16* kp = qkv + (size_t)(b * NPd + sidx) * 3072 + Cd + hh * 64 + dd;
        const u16* vp = kp + Cd;
        *(ulonglong2*)&kv16[0] = *(const ulonglong2*)kp;
        *(ulonglong2*)&kv16[8] = *(const ulonglong2*)(kp + 8);
        *(ulonglong2*)&vv16[0] = *(const ulonglong2*)vp;
        *(ulonglong2*)&vv16[8] = *(const ulonglong2*)(vp + 8);
    } else {
        const float* kp = ck + ((size_t)((b * Hd + hh) * Nd + n)) * HDd + dd;
        const float* vp = cv + ((size_t)((b * Hd + hh) * Nd + n)) * HDd + dd;
        #pragma unroll
        for (int c = 0; c < 4; c++) {
            const float4 kc4 = *(const float4*)(kp + c * 4);
            const float4 vc4 = *(const float4*)(vp + c * 4);
            kv16[c * 4 + 0] = f2bf(kc4.x); kv16[c * 4 + 1] = f2bf(kc4.y);
            kv16[c * 4 + 2] = f2bf(kc4.z); kv16[c * 4 + 3] = f2bf(kc4.w);
            vv16[c * 4 + 0] = f2bf(vc4.x); vv16[c * 4 + 1] = f2bf(vc4.y);
            vv16[c * 4 + 2] = f2bf(vc4.z); vv16[c * 4 + 3] = f2bf(vc4.w);
        }
    }

    u16* ko = Kb + ((size_t)((b * Hd + hh) * Nd + n)) * HDd + dd;
    *(ulonglong2*)ko = *(ulonglong2*)&kv16[0];
    *(ulonglong2*)(ko + 8) = *(ulonglong2*)&kv16[8];

    #pragma unroll
    for (int i = 0; i < 16; i++) Vl[row][dd + i] = vv16[i];
    __syncthreads();

    const int d = t >> 2, nc = (t & 3) * 16;
    u16 ov[16];
    #pragma unroll
    for (int i = 0; i < 16; i++) ov[i] = Vl[nc + i][d];
    u16* vo = Vtb + ((size_t)((b * Hd + hh) * HDd + d)) * Nd + nt * 64 + nc;
    *(ulonglong2*)vo = *(ulonglong2*)&ov[0];
    *(ulonglong2*)(vo + 8) = *(ulonglong2*)&ov[8];
}

// ---------------------------------------------------------------------------
// MFMA flash attention. Grid (bh=256, qt=8), 256 thr = 4 waves.
// Swapped QK^T (S^T = mfma(K,Q)) softmax; packed P writes; defer-max.
// NEW (R9): double-buffered K/V staging — issue tile kt+1's global_load_lds
// BEFORE computing tile kt, single vmcnt(0)+barrier per iteration (was:
// barrier -> issue -> drain-barrier with zero overlap — the same serial
// pattern that cost the GEMMs 20% before R3). Q frags hoisted fully out of
// the loop. LDS 50 KB -> 3 blocks/CU (was 4); overlap should dominate.
// XCD remap keeps per-XCD KV working set ~2MB (L2-resident).
// ---------------------------------------------------------------------------
__global__ __launch_bounds__(256) void attn_mfma(const u16* __restrict__ qkv,
                                                 const u16* __restrict__ Kb,
                                                 const u16* __restrict__ Vtb,
                                                 u16* __restrict__ attno) {
    const int orig = blockIdx.y * 256 + blockIdx.x;
    const int xc = orig & 7, pos = orig >> 3;
    const int bh = (xc << 5) | (pos >> 3);
    const int qt = pos & 7;
    const int b = bh >> 4, hh = bh & 15;
    const int t = threadIdx.x;
    const int L = t & 63;
    const int w = t >> 6;
    const int g = L >> 4;        // 0..3: key sub-group / k-chunk
    const int q16 = L & 15;      // lane's softmax q (within wave block)

    __shared__ u16 Qs[4096];          // [64 q][64 k] swizzled
    __shared__ u16 Ks[2][4096];       // dbuf [64 key][64 dim] swizzled
    __shared__ u16 Vs[2][4096];       // dbuf [64 dim][64 key] swizzled
    __shared__ u16 Ps[4][16 * 72];    // per-wave P [16 q][64 key], pad 72

    const size_t kbase = (size_t)((b * Hd + hh) * Nd) * HDd;
    const size_t vbase = (size_t)((b * Hd + hh) * HDd) * Nd;

    // per-wave staging geometry (wave w owns rows 16w..16w+15 of each tile)
    const int srow0 = 16 * w + (L >> 3);          // j=0 row
    const int sch0  = (L & 7) ^ (srow0 & 7);
    const int srow1 = srow0 + 8;                  // j=1 row
    const int sch1  = (L & 7) ^ (srow1 & 7);

#define STAGE_KV(buf_, kt_) do {                                              \
        async_load16(Kb + kbase + (size_t)((kt_) * 64 + srow0) * 64 + sch0 * 8, \
                     Ks[buf_] + (16 * w) * 64);                               \
        async_load16(Vtb + vbase + (size_t)srow0 * Nd + (kt_) * 64 + sch0 * 8, \
                     Vs[buf_] + (16 * w) * 64);                               \
        async_load16(Kb + kbase + (size_t)((kt_) * 64 + srow1) * 64 + sch1 * 8, \
                     Ks[buf_] + (16 * w + 8) * 64);                           \
        async_load16(Vtb + vbase + (size_t)srow1 * Nd + (kt_) * 64 + sch1 * 8, \
                     Vs[buf_] + (16 * w + 8) * 64);                           \
    } while (0)

    // prologue: stage Q and tile 0, drain, barrier
    async_load16(qkv + (size_t)(b * NPd + qt * 64 + srow0) * 3072 + hh * 64 + sch0 * 8,
                 Qs + (16 * w) * 64);
    async_load16(qkv + (size_t)(b * NPd + qt * 64 + srow1) * 3072 + hh * 64 + sch1 * 8,
                 Qs + (16 * w + 8) * 64);
    STAGE_KV(0, 0);
    asm volatile("s_waitcnt vmcnt(0)" ::: "memory");
    __builtin_amdgcn_s_barrier();

    // hoisted Q A-frags (rows w*16 + q16) — Qs is dead after this
    const int qrow = 16 * w + q16;
    const bf16x8 aq0 = *(const bf16x8*)&Qs[qrow * 64 + ((g       ^ (L & 7)) * 8)];
    const bf16x8 aq1 = *(const bf16x8*)&Qs[qrow * 64 + (((4 + g) ^ (L & 7)) * 8)];

    f32x4 acc[4];
    const f32x4 zero = {0.f, 0.f, 0.f, 0.f};
    #pragma unroll
    for (int nb = 0; nb < 4; nb++) acc[nb] = zero;
    float m_run = -INFINITY;   // running max for q = w*16+q16 (scaled units)
    float l_run = 0.f;         // running denom for q = w*16+q16

    for (int kt = 0; kt < 16; kt++) {
        const int cur = kt & 1;
        // overlap: issue next tile's staging before this tile's compute
        if (kt < 15) STAGE_KV(cur ^ 1, kt + 1);

        // S^T = K Q^T: swapped operands. s[kb][r] = S[q=w*16+q16][key=kb*16+g*4+r]
        f32x4 s[4];
        #pragma unroll
        for (int kb = 0; kb < 4; kb++) {
            const int krow = kb * 16 + q16;
            const bf16x8 bk0 = *(const bf16x8*)&Ks[cur][krow * 64 + ((g       ^ (L & 7)) * 8)];
            const bf16x8 bk1 = *(const bf16x8*)&Ks[cur][krow * 64 + (((4 + g) ^ (L & 7)) * 8)];
            s[kb] = __builtin_amdgcn_mfma_f32_16x16x32_bf16(bk0, aq0, zero, 0, 0, 0);
            s[kb] = __builtin_amdgcn_mfma_f32_16x16x32_bf16(bk1, aq1, s[kb], 0, 0, 0);
        }

        // in-register row max (16 values for this lane's q), then 2 shfl
        float m0 = fmaxf(fmaxf(s[0][0], s[0][1]), fmaxf(s[0][2], s[0][3]));
        float m1 = fmaxf(fmaxf(s[1][0], s[1][1]), fmaxf(s[1][2], s[1][3]));
        float m2 = fmaxf(fmaxf(s[2][0], s[2][1]), fmaxf(s[2][2], s[2][3]));
        float m3 = fmaxf(fmaxf(s[3][0], s[3][1]), fmaxf(s[3][2], s[3][3]));
        float mx = fmaxf(fmaxf(m0, m1), fmaxf(m2, m3)) * 0.125f;
        mx = fmaxf(mx, __shfl_xor(mx, 16));
        mx = fmaxf(mx, __shfl_xor(mx, 32));

        // defer-max: rescale only if some q's max grew past threshold
        if (__any(mx > m_run + 8.f)) {
            const float mn = fmaxf(m_run, mx);
            const float al = __expf(m_run - mn);
            m_run = mn;
            l_run *= al;
            float alr[4];
            #pragma unroll
            for (int r = 0; r < 4; r++) alr[r] = __shfl(al, g * 4 + r);
            #pragma unroll
            for (int nb = 0; nb < 4; nb++)
                #pragma unroll
                for (int r = 0; r < 4; r++) acc[nb][r] *= alr[r];
        }

        // P = exp(S*scale - m), packed write + in-register sum
        u16* pw = &Ps[w][0];
        float ps = 0.f;
        #pragma unroll
        for (int kb = 0; kb < 4; kb++) {
            float p0 = __expf(fmaf(s[kb][0], 0.125f, -m_run));
            float p1 = __expf(fmaf(s[kb][1], 0.125f, -m_run));
            float p2 = __expf(fmaf(s[kb][2], 0.125f, -m_run));
            float p3 = __expf(fmaf(s[kb][3], 0.125f, -m_run));
            ps += (p0 + p1) + (p2 + p3);
            ushort4 v4;
            v4.x = f2bf(p0); v4.y = f2bf(p1); v4.z = f2bf(p2); v4.w = f2bf(p3);
            *(ushort4*)&pw[q16 * 72 + kb * 16 + g * 4] = v4;
        }
        ps += __shfl_xor(ps, 16);
        ps += __shfl_xor(ps, 32);
        l_run += ps;

        // PV: A = P [q][key], B = Vt [dim][key]
        const bf16x8 ap0 = *(const bf16x8*)&Ps[w][q16 * 72 +      g * 8];
        const bf16x8 ap1 = *(const bf16x8*)&Ps[w][q16 * 72 + 32 + g * 8];
        #pragma unroll
        for (int nb = 0; nb < 4; nb++) {
            const int drow = nb * 16 + q16;
            const bf16x8 bv0 = *(const bf16x8*)&Vs[cur][drow * 64 + ((g       ^ (L & 7)) * 8)];
            const bf16x8 bv1 = *(const bf16x8*)&Vs[cur][drow * 64 + (((4 + g) ^ (L & 7)) * 8)];
            acc[nb] = __builtin_amdgcn_mfma_f32_16x16x32_bf16(ap0, bv0, acc[nb], 0, 0, 0);
            acc[nb] = __builtin_amdgcn_mfma_f32_16x16x32_bf16(ap1, bv1, acc[nb], 0, 0, 0);
        }

        // next tile's staging complete + all waves done reading cur
        asm volatile("s_waitcnt vmcnt(0)" ::: "memory");
        __builtin_amdgcn_s_barrier();
    }
#undef STAGE_KV

    // redistribute 1/l to this lane's acc rows (q' = g*4+r)
    const float invq = 1.0f / l_run;
    float inv[4];
    #pragma unroll
    for (int r = 0; r < 4; r++) inv[r] = __shfl(invq, g * 4 + r);
    #pragma unroll
    for (int nb = 0; nb < 4; nb++)
        #pragma unroll
        for (int r = 0; r < 4; r++) {
            const int q = qt * 64 + w * 16 + g * 4 + r;
            const int d = nb * 16 + q16;
            attno[(size_t)(b * NPd + q) * Cd + hh * 64 + d] = f2bf(acc[nb][r] * inv[r]);
        }
}

// ---------------------------------------------------------------------------
extern "C" void kernel_launch(void* const* d_in, const int* in_sizes, int n_in,
                              void* d_out, int out_size, void* d_ws, size_t ws_size,
                              hipStream_t stream) {
    const float* x       = (const float*)d_in[0];
    const float* cache_k = (const float*)d_in[1];
    const float* cache_v = (const float*)d_in[2];
    const void*  mask    = d_in[3];
    const float* qkv_w   = (const float*)d_in[4];
    const float* qkv_b   = (const float*)d_in[5];
    const float* proj_w  = (const float*)d_in[6];
    const float* proj_b  = (const float*)d_in[7];
    const float* n1_g    = (const float*)d_in[8];
    const float* n1_b    = (const float*)d_in[9];
    const float* n2_g    = (const float*)d_in[10];
    const float* n2_b    = (const float*)d_in[11];
    const float* fc1_w   = (const float*)d_in[12];
    const float* fc1_b   = (const float*)d_in[13];
    const float* fc2_w   = (const float*)d_in[14];
    const float* fc2_b   = (const float*)d_in[15];
    float* out = (float*)d_out;

    const size_t MR = (size_t)Bd * NPd;           // 8192 rows
    char* ws = (char*)d_ws;
    int*   srcArr = (int*)ws;                                     // 64 KB
    float* x2     = (float*)(ws + 65536);                         // 33.55 MB
    u16*   h      = (u16*)(x2 + MR * Cd);                         // 16.78 MB
    u16*   attno  = h + MR * Cd;                                  // 16.78 MB
    u16*   qkv    = attno + MR * Cd;                              // 50.33 MB bf16
    u16*   Kb     = qkv + MR * 3 * Cd;                            // 33.55 MB
    u16*   Vtb    = Kb + (size_t)Bd * Hd * Nd * HDd;              // 33.55 MB
    u16*   m1     = qkv;            // 67.1 MB, reuses dead qkv+Kb region
    u16*   qkv_wt = Vtb + (size_t)Bd * Hd * Nd * HDd;             // 6.29 MB
    u16*   proj_wt= qkv_wt + (size_t)3 * Cd * Cd;                 // 2.10 MB
    u16*   fc1_wt = proj_wt + (size_t)Cd * Cd;                    // 8.39 MB
    u16*   fc2_wt = fc1_wt + (size_t)Cd * HIDd;                   // 8.39 MB

    build_src<<<Bd, 256, 0, stream>>>(mask, srcArr);
    conv_t<<<dim3(3 * Cd / 32, Cd / 32),  256, 0, stream>>>(qkv_w,  qkv_wt,  Cd,   3 * Cd);
    conv_t<<<dim3(Cd / 32, Cd / 32),      256, 0, stream>>>(proj_w, proj_wt, Cd,   Cd);
    conv_t<<<dim3(HIDd / 32, Cd / 32),    256, 0, stream>>>(fc1_w,  fc1_wt,  Cd,   HIDd);
    conv_t<<<dim3(Cd / 32, HIDd / 32),    256, 0, stream>>>(fc2_w,  fc2_wt,  HIDd, Cd);

    ln_kernel<<<MR, 256, 0, stream>>>(x, n1_g, n1_b, h);
    gemm_mfma<0, u16><<<dim3(3 * Cd / 128, MR / 128), 256, 0, stream>>>(
        h, qkv_wt, qkv_b, nullptr, qkv, Cd, 3 * Cd);
    kv_cast<<<Bd * Hd * (Nd / 64), 256, 0, stream>>>(qkv, cache_k, cache_v, srcArr, Kb, Vtb);
    attn_mfma<<<dim3(Bd * Hd, NPd / 64), 256, 0, stream>>>(qkv, Kb, Vtb, attno);
    gemm_mfma<1, float><<<dim3(Cd / 128, MR / 128), 256, 0, stream>>>(
        attno, proj_wt, proj_b, x, x2, Cd, Cd);
    ln_kernel<<<MR, 256, 0, stream>>>(x2, n2_g, n2_b, h);
    gemm_mfma<2, u16><<<dim3(HIDd / 128, MR / 128), 256, 0, stream>>>(
        h, fc1_wt, fc1_b, nullptr, m1, Cd, HIDd);
    gemm_mfma<1, float><<<dim3(Cd / 128, MR / 128), 256, 0, stream>>>(
        m1, fc2_wt, fc2_b, x2, out, HIDd, Cd);
}